// Round 1
// baseline (2441.642 us; speedup 1.0000x reference)
//
#include <hip/hip_runtime.h>
#include <hip/hip_bf16.h>
#include <math.h>

#define TT 2048
#define CC 1024
#define HH 16
#define DD 64
#define LL 4
#define VOCAB_N 32000

using bf16 = __hip_bfloat16;
typedef __bf16 bf16x8 __attribute__((ext_vector_type(8)));
typedef float f32x4 __attribute__((ext_vector_type(4)));

typedef unsigned int uint_gl __attribute__((address_space(1)));
typedef unsigned int uint_ld __attribute__((address_space(3)));

__device__ __forceinline__ void gload_lds16(const bf16* g, bf16* l) {
    __builtin_amdgcn_global_load_lds((const uint_gl*)g, (uint_ld*)l, 16, 0, 0);
}

// ---------------- embed: x = wte[ids] + wpe ----------------
__global__ __launch_bounds__(256) void embed_kernel(const int* __restrict__ ids,
                                                    const float* __restrict__ wte,
                                                    const float* __restrict__ wpe,
                                                    float* __restrict__ x) {
    int t = blockIdx.x;
    int id = ids[t];
    int tid = threadIdx.x;
    float4 a = ((const float4*)(wte + (size_t)id * CC))[tid];
    float4 p = ((const float4*)(wpe + (size_t)t * CC))[tid];
    a.x += p.x; a.y += p.y; a.z += p.z; a.w += p.w;
    ((float4*)(x + (size_t)t * CC))[tid] = a;
}

// ---------------- layernorm (fp32 in, bf16 out), one block per row ----------------
__global__ __launch_bounds__(256) void ln_kernel(const float* __restrict__ x,
                                                 const float* __restrict__ w,
                                                 const float* __restrict__ b,
                                                 bf16* __restrict__ out) {
    int row = blockIdx.x;
    int tid = threadIdx.x;
    const float* xr = x + (size_t)row * CC;
    float4 v = ((const float4*)xr)[tid];
    float s = v.x + v.y + v.z + v.w;
    float ss = v.x * v.x + v.y * v.y + v.z * v.z + v.w * v.w;
    #pragma unroll
    for (int off = 32; off > 0; off >>= 1) {
        s += __shfl_down(s, off, 64);
        ss += __shfl_down(ss, off, 64);
    }
    __shared__ float sbuf[8];
    int wv = tid >> 6;
    if ((tid & 63) == 0) { sbuf[wv] = s; sbuf[4 + wv] = ss; }
    __syncthreads();
    s = sbuf[0] + sbuf[1] + sbuf[2] + sbuf[3];
    ss = sbuf[4] + sbuf[5] + sbuf[6] + sbuf[7];
    float mu = s * (1.0f / CC);
    float var = ss * (1.0f / CC) - mu * mu;
    float rs = rsqrtf(var + 1e-5f);
    float4 wv4 = ((const float4*)w)[tid];
    float4 bv4 = ((const float4*)b)[tid];
    size_t base = (size_t)row * CC + tid * 4;
    out[base + 0] = __float2bfloat16((v.x - mu) * rs * wv4.x + bv4.x);
    out[base + 1] = __float2bfloat16((v.y - mu) * rs * wv4.y + bv4.y);
    out[base + 2] = __float2bfloat16((v.z - mu) * rs * wv4.z + bv4.z);
    out[base + 3] = __float2bfloat16((v.w - mu) * rs * wv4.w + bv4.w);
}

// ---------------- fp32 -> bf16 convert ----------------
__global__ __launch_bounds__(256) void cvt_kernel(const float* __restrict__ in,
                                                  bf16* __restrict__ out, int n) {
    int i = (blockIdx.x * 256 + threadIdx.x) * 4;
    if (i < n) {
        float4 v = *(const float4*)(in + i);
        out[i + 0] = __float2bfloat16(v.x);
        out[i + 1] = __float2bfloat16(v.y);
        out[i + 2] = __float2bfloat16(v.z);
        out[i + 3] = __float2bfloat16(v.w);
    }
}

// ---------------- GEMM: out(M,N) = A(M,K) @ W(N,K)^T + bias ----------------
// EPI: 0 = bf16 store (+bias), 1 = bf16 store gelu(v+bias), 2 = fp32 residual add (+bias), 3 = fp32 store (no bias)
template <int EPI>
__global__ __launch_bounds__(256) void gemm_bt(const bf16* __restrict__ A,
                                               const bf16* __restrict__ W,
                                               const float* __restrict__ bias,
                                               bf16* __restrict__ outb,
                                               float* __restrict__ outf,
                                               int M, int N, int K) {
    __shared__ bf16 At[128 * 32];
    __shared__ bf16 Bt[128 * 32];
    const int tid = threadIdx.x;
    const int wv = tid >> 6;
    const int ln = tid & 15;
    const int quad = (tid & 63) >> 4;
    const int wm = (wv >> 1) * 64;
    const int wn = (wv & 1) * 64;
    const int m0 = blockIdx.y * 128;
    const int n0 = blockIdx.x * 128;

    f32x4 acc[4][4];
    #pragma unroll
    for (int i = 0; i < 4; i++)
        #pragma unroll
        for (int j = 0; j < 4; j++)
            #pragma unroll
            for (int r = 0; r < 4; r++) acc[i][j][r] = 0.0f;

    for (int k0 = 0; k0 < K; k0 += 32) {
        #pragma unroll
        for (int r = 0; r < 2; r++) {
            int ci = r * 256 + tid;
            gload_lds16(A + (size_t)(m0 + (ci >> 2)) * K + k0 + (ci & 3) * 8,
                        At + (size_t)(r * 256 + wv * 64) * 8);
            gload_lds16(W + (size_t)(n0 + (ci >> 2)) * K + k0 + (ci & 3) * 8,
                        Bt + (size_t)(r * 256 + wv * 64) * 8);
        }
        __syncthreads();
        bf16x8 af[4], bfg[4];
        #pragma unroll
        for (int i = 0; i < 4; i++) af[i] = *(const bf16x8*)&At[(wm + i * 16 + ln) * 32 + quad * 8];
        #pragma unroll
        for (int j = 0; j < 4; j++) bfg[j] = *(const bf16x8*)&Bt[(wn + j * 16 + ln) * 32 + quad * 8];
        #pragma unroll
        for (int i = 0; i < 4; i++)
            #pragma unroll
            for (int j = 0; j < 4; j++)
                acc[i][j] = __builtin_amdgcn_mfma_f32_16x16x32_bf16(af[i], bfg[j], acc[i][j], 0, 0, 0);
        __syncthreads();
    }

    #pragma unroll
    for (int j = 0; j < 4; j++) {
        int col = n0 + wn + j * 16 + ln;
        float bv = (EPI == 3) ? 0.0f : bias[col];
        #pragma unroll
        for (int i = 0; i < 4; i++) {
            int rowb = m0 + wm + i * 16 + quad * 4;
            #pragma unroll
            for (int r = 0; r < 4; r++) {
                float v = acc[i][j][r] + bv;
                size_t idx = (size_t)(rowb + r) * N + col;
                if (EPI == 0) {
                    outb[idx] = __float2bfloat16(v);
                } else if (EPI == 1) {
                    outb[idx] = __float2bfloat16(0.5f * v * (1.0f + erff(v * 0.70710678118654752f)));
                } else if (EPI == 2) {
                    outf[idx] += v;
                } else {
                    outf[idx] = v;
                }
            }
        }
    }
}

// ---------------- flash attention (causal), bf16 qkv in, bf16 y out ----------------
// grid: (H, T/128). block 256 threads = 4 waves; wave handles 32 q-rows.
__global__ __launch_bounds__(256) void attn_kernel(const bf16* __restrict__ qkv,
                                                   bf16* __restrict__ y) {
    const int h = blockIdx.x;
    const int q0 = blockIdx.y * 128;
    const int tid = threadIdx.x;
    const int wq = tid >> 6;
    const int ln = tid & 15;
    const int quad = (tid & 63) >> 4;
    const int wr0 = q0 + wq * 32;

    __shared__ bf16 Kt[64 * 72];
    __shared__ bf16 Vt[64 * 72];
    __shared__ bf16 Pt[4][32 * 72];

    // Q fragments (A-operand layout), rows wr0..wr0+31, D=64 -> 2 k-steps
    bf16x8 qf[2][2];
    #pragma unroll
    for (int i = 0; i < 2; i++)
        #pragma unroll
        for (int ks = 0; ks < 2; ks++)
            qf[i][ks] = *(const bf16x8*)(qkv + (size_t)(wr0 + i * 16 + ln) * (3 * CC) + h * DD + ks * 32 + quad * 8);

    f32x4 oy[2][4];
    float mrow[2][4], lrow[2][4];
    #pragma unroll
    for (int i = 0; i < 2; i++)
        #pragma unroll
        for (int j = 0; j < 4; j++) {
            #pragma unroll
            for (int r = 0; r < 4; r++) oy[i][j][r] = 0.0f;
            mrow[i][j] = -INFINITY;
            lrow[i][j] = 0.0f;
        }

    const int ntiles = q0 / 64 + 2;
    for (int kt = 0; kt < ntiles; kt++) {
        const int kt0 = kt * 64;
        // stage K tile (64 x 64) -> Kt (row-major, stride 72)
        #pragma unroll
        for (int r = 0; r < 2; r++) {
            int ci = r * 256 + tid;              // 512 chunks of 8
            int krow = ci >> 3, kcol = (ci & 7) * 8;
            *(bf16x8*)&Kt[krow * 72 + kcol] =
                *(const bf16x8*)(qkv + (size_t)(kt0 + krow) * (3 * CC) + CC + h * DD + kcol);
        }
        // stage V^T: Vt[n][k] = V[kt0+k][n], stride 72
        #pragma unroll
        for (int r = 0; r < 16; r++) {
            int f = r * 256 + tid;
            int vr = f >> 6, vn = f & 63;
            Vt[vn * 72 + vr] = qkv[(size_t)(kt0 + vr) * (3 * CC) + 2 * CC + h * DD + vn];
        }
        __syncthreads();

        if (kt0 <= wr0) {
            // S = Q @ K^T (wave: 32 x 64)
            f32x4 sc[2][4];
            #pragma unroll
            for (int i = 0; i < 2; i++)
                #pragma unroll
                for (int j = 0; j < 4; j++)
                    #pragma unroll
                    for (int r = 0; r < 4; r++) sc[i][j][r] = 0.0f;
            bf16x8 kf[4][2];
            #pragma unroll
            for (int jt = 0; jt < 4; jt++)
                #pragma unroll
                for (int ks = 0; ks < 2; ks++)
                    kf[jt][ks] = *(const bf16x8*)&Kt[(jt * 16 + ln) * 72 + ks * 32 + quad * 8];
            #pragma unroll
            for (int ks = 0; ks < 2; ks++)
                #pragma unroll
                for (int i = 0; i < 2; i++)
                    #pragma unroll
                    for (int jt = 0; jt < 4; jt++)
                        sc[i][jt] = __builtin_amdgcn_mfma_f32_16x16x32_bf16(qf[i][ks], kf[jt][ks], sc[i][jt], 0, 0, 0);

            const float scale = 0.125f;  // 1/sqrt(64)
            #pragma unroll
            for (int i = 0; i < 2; i++) {
                #pragma unroll
                for (int r = 0; r < 4; r++) {
                    int row = wr0 + i * 16 + quad * 4 + r;
                    float sv[4];
                    float mx = -INFINITY;
                    #pragma unroll
                    for (int jt = 0; jt < 4; jt++) {
                        int col = kt0 + jt * 16 + ln;
                        float t = sc[i][jt][r] * scale;
                        if (col > row) t = -INFINITY;
                        sv[jt] = t;
                        mx = fmaxf(mx, t);
                    }
                    #pragma unroll
                    for (int off = 1; off < 16; off <<= 1) mx = fmaxf(mx, __shfl_xor(mx, off, 16));
                    float mnew = fmaxf(mrow[i][r], mx);
                    float alpha = __expf(mrow[i][r] - mnew);
                    mrow[i][r] = mnew;
                    float psum = 0.0f;
                    #pragma unroll
                    for (int jt = 0; jt < 4; jt++) {
                        float p = __expf(sv[jt] - mnew);
                        psum += p;
                        Pt[wq][(i * 16 + quad * 4 + r) * 72 + jt * 16 + ln] = __float2bfloat16(p);
                    }
                    #pragma unroll
                    for (int off = 1; off < 16; off <<= 1) psum += __shfl_xor(psum, off, 16);
                    lrow[i][r] = lrow[i][r] * alpha + psum;
                    #pragma unroll
                    for (int jn = 0; jn < 4; jn++) oy[i][jn][r] *= alpha;
                }
            }

            // O += P @ V   (P: 32x64 in A-layout via LDS, V^T in LDS as B-operand)
            bf16x8 pf[2][2], vf[4][2];
            #pragma unroll
            for (int i = 0; i < 2; i++)
                #pragma unroll
                for (int ks = 0; ks < 2; ks++)
                    pf[i][ks] = *(const bf16x8*)&Pt[wq][(i * 16 + ln) * 72 + ks * 32 + quad * 8];
            #pragma unroll
            for (int jn = 0; jn < 4; jn++)
                #pragma unroll
                for (int ks = 0; ks < 2; ks++)
                    vf[jn][ks] = *(const bf16x8*)&Vt[(jn * 16 + ln) * 72 + ks * 32 + quad * 8];
            #pragma unroll
            for (int ks = 0; ks < 2; ks++)
                #pragma unroll
                for (int i = 0; i < 2; i++)
                    #pragma unroll
                    for (int jn = 0; jn < 4; jn++)
                        oy[i][jn] = __builtin_amdgcn_mfma_f32_16x16x32_bf16(pf[i][ks], vf[jn][ks], oy[i][jn], 0, 0, 0);
        }
        __syncthreads();
    }

    // epilogue: y = O / l
    #pragma unroll
    for (int i = 0; i < 2; i++)
        #pragma unroll
        for (int jn = 0; jn < 4; jn++)
            #pragma unroll
            for (int r = 0; r < 4; r++) {
                int row = wr0 + i * 16 + quad * 4 + r;
                int col = h * DD + jn * 16 + ln;
                y[(size_t)row * CC + col] = __float2bfloat16(oy[i][jn][r] / lrow[i][r]);
            }
}

// ---------------- launch ----------------
extern "C" void kernel_launch(void* const* d_in, const int* in_sizes, int n_in,
                              void* d_out, int out_size, void* d_ws, size_t ws_size,
                              hipStream_t stream) {
    const int*   ids    = (const int*)d_in[0];
    const float* wte    = (const float*)d_in[1];
    const float* wpe    = (const float*)d_in[2];
    const float* ln1_w  = (const float*)d_in[3];
    const float* ln1_b  = (const float*)d_in[4];
    const float* attn_w = (const float*)d_in[5];
    const float* attn_b = (const float*)d_in[6];
    const float* proj_w = (const float*)d_in[7];
    const float* proj_b = (const float*)d_in[8];
    const float* ln2_w  = (const float*)d_in[9];
    const float* ln2_b  = (const float*)d_in[10];
    const float* fc_w   = (const float*)d_in[11];
    const float* fc_b   = (const float*)d_in[12];
    const float* fcp_w  = (const float*)d_in[13];
    const float* fcp_b  = (const float*)d_in[14];
    const float* lnf_w  = (const float*)d_in[15];
    const float* lnf_b  = (const float*)d_in[16];

    char* ws = (char*)d_ws;
    float* x    = (float*)(ws);                     // 8 MB fp32 residual
    bf16* hbuf  = (bf16*)(ws + 8388608);            // 4 MB  (T x C)
    bf16* g4buf = (bf16*)(ws + 12582912);           // 16 MB (T x 4C)
    bf16* qkvb  = (bf16*)(ws + 29360128);           // 12 MB (T x 3C)
    bf16* ybuf  = (bf16*)(ws + 41943040);           // 4 MB  (T x C)
    bf16* wbuf  = (bf16*)(ws + 46137344);           // 62.5 MB (max VOCAB x C)

    embed_kernel<<<TT, 256, 0, stream>>>(ids, wte, wpe, x);

    for (int l = 0; l < LL; l++) {
        ln_kernel<<<TT, 256, 0, stream>>>(x, ln1_w + l * CC, ln1_b + l * CC, hbuf);

        cvt_kernel<<<(3 * CC * CC) / 1024, 256, 0, stream>>>(attn_w + (size_t)l * 3 * CC * CC, wbuf, 3 * CC * CC);
        gemm_bt<0><<<dim3(3 * CC / 128, TT / 128), 256, 0, stream>>>(hbuf, wbuf, attn_b + l * 3 * CC,
                                                                     qkvb, nullptr, TT, 3 * CC, CC);

        attn_kernel<<<dim3(HH, TT / 128), 256, 0, stream>>>(qkvb, ybuf);

        cvt_kernel<<<(CC * CC) / 1024, 256, 0, stream>>>(proj_w + (size_t)l * CC * CC, wbuf, CC * CC);
        gemm_bt<2><<<dim3(CC / 128, TT / 128), 256, 0, stream>>>(ybuf, wbuf, proj_b + l * CC,
                                                                 nullptr, x, TT, CC, CC);

        ln_kernel<<<TT, 256, 0, stream>>>(x, ln2_w + l * CC, ln2_b + l * CC, hbuf);

        cvt_kernel<<<(4 * CC * CC) / 1024, 256, 0, stream>>>(fc_w + (size_t)l * 4 * CC * CC, wbuf, 4 * CC * CC);
        gemm_bt<1><<<dim3(4 * CC / 128, TT / 128), 256, 0, stream>>>(hbuf, wbuf, fc_b + l * 4 * CC,
                                                                     g4buf, nullptr, TT, 4 * CC, CC);

        cvt_kernel<<<(4 * CC * CC) / 1024, 256, 0, stream>>>(fcp_w + (size_t)l * 4 * CC * CC, wbuf, 4 * CC * CC);
        gemm_bt<2><<<dim3(CC / 128, TT / 128), 256, 0, stream>>>(g4buf, wbuf, fcp_b + l * CC,
                                                                 nullptr, x, TT, CC, 4 * CC);
    }

    ln_kernel<<<TT, 256, 0, stream>>>(x, lnf_w, lnf_b, hbuf);
    cvt_kernel<<<(VOCAB_N * CC) / 1024, 256, 0, stream>>>(wte, wbuf, VOCAB_N * CC);
    gemm_bt<3><<<dim3(VOCAB_N / 128, TT / 128), 256, 0, stream>>>(hbuf, wbuf, nullptr,
                                                                  nullptr, (float*)d_out, TT, VOCAB_N, CC);
}

// Round 2
// 1580.667 us; speedup vs baseline: 1.5447x; 1.5447x over previous
//
#include <hip/hip_runtime.h>
#include <hip/hip_bf16.h>
#include <math.h>

#define TT 2048
#define CC 1024
#define HH 16
#define DD 64
#define LL 4
#define VOCAB_N 32000

using bf16 = __hip_bfloat16;
typedef __bf16 bf16x8 __attribute__((ext_vector_type(8)));
typedef float f32x4 __attribute__((ext_vector_type(4)));

typedef unsigned int uint_gl __attribute__((address_space(1)));
typedef unsigned int uint_ld __attribute__((address_space(3)));

__device__ __forceinline__ void gload_lds16(const bf16* g, bf16* l) {
    __builtin_amdgcn_global_load_lds((const uint_gl*)g, (uint_ld*)l, 16, 0, 0);
}

// ---------------- embed: x = wte[ids] + wpe ----------------
__global__ __launch_bounds__(256) void embed_kernel(const int* __restrict__ ids,
                                                    const float* __restrict__ wte,
                                                    const float* __restrict__ wpe,
                                                    float* __restrict__ x) {
    int t = blockIdx.x;
    int id = ids[t];
    int tid = threadIdx.x;
    float4 a = ((const float4*)(wte + (size_t)id * CC))[tid];
    float4 p = ((const float4*)(wpe + (size_t)t * CC))[tid];
    a.x += p.x; a.y += p.y; a.z += p.z; a.w += p.w;
    ((float4*)(x + (size_t)t * CC))[tid] = a;
}

// ---------------- layernorm (fp32 in, bf16 out), one block per row ----------------
__global__ __launch_bounds__(256) void ln_kernel(const float* __restrict__ x,
                                                 const float* __restrict__ w,
                                                 const float* __restrict__ b,
                                                 bf16* __restrict__ out) {
    int row = blockIdx.x;
    int tid = threadIdx.x;
    const float* xr = x + (size_t)row * CC;
    float4 v = ((const float4*)xr)[tid];
    float s = v.x + v.y + v.z + v.w;
    float ss = v.x * v.x + v.y * v.y + v.z * v.z + v.w * v.w;
    #pragma unroll
    for (int off = 32; off > 0; off >>= 1) {
        s += __shfl_down(s, off, 64);
        ss += __shfl_down(ss, off, 64);
    }
    __shared__ float sbuf[8];
    int wv = tid >> 6;
    if ((tid & 63) == 0) { sbuf[wv] = s; sbuf[4 + wv] = ss; }
    __syncthreads();
    s = sbuf[0] + sbuf[1] + sbuf[2] + sbuf[3];
    ss = sbuf[4] + sbuf[5] + sbuf[6] + sbuf[7];
    float mu = s * (1.0f / CC);
    float var = ss * (1.0f / CC) - mu * mu;
    float rs = rsqrtf(var + 1e-5f);
    float4 wv4 = ((const float4*)w)[tid];
    float4 bv4 = ((const float4*)b)[tid];
    size_t base = (size_t)row * CC + tid * 4;
    out[base + 0] = __float2bfloat16((v.x - mu) * rs * wv4.x + bv4.x);
    out[base + 1] = __float2bfloat16((v.y - mu) * rs * wv4.y + bv4.y);
    out[base + 2] = __float2bfloat16((v.z - mu) * rs * wv4.z + bv4.z);
    out[base + 3] = __float2bfloat16((v.w - mu) * rs * wv4.w + bv4.w);
}

// ---------------- fp32 -> bf16 convert ----------------
__global__ __launch_bounds__(256) void cvt_kernel(const float* __restrict__ in,
                                                  bf16* __restrict__ out, int n) {
    int i = (blockIdx.x * 256 + threadIdx.x) * 4;
    if (i < n) {
        float4 v = *(const float4*)(in + i);
        out[i + 0] = __float2bfloat16(v.x);
        out[i + 1] = __float2bfloat16(v.y);
        out[i + 2] = __float2bfloat16(v.z);
        out[i + 3] = __float2bfloat16(v.w);
    }
}

// ---------------- GEMM: out(M,N) = A(M,K) @ W(N,K)^T + bias ----------------
// EPI: 0 = bf16 store (+bias), 1 = bf16 store gelu(v+bias), 2 = fp32 residual add (+bias), 3 = fp32 store (no bias)
// KSPLIT: blockIdx.z splits K; EPI=2 uses atomicAdd when KSPLIT>1.
template <int EPI, int KSPLIT>
__global__ __launch_bounds__(256) void gemm_bt(const bf16* __restrict__ A,
                                               const bf16* __restrict__ W,
                                               const float* __restrict__ bias,
                                               bf16* __restrict__ outb,
                                               float* __restrict__ outf,
                                               int M, int N, int K) {
    __shared__ bf16 At[128 * 32];
    __shared__ bf16 Bt[128 * 32];
    const int tid = threadIdx.x;
    const int wv = tid >> 6;
    const int ln = tid & 15;
    const int quad = (tid & 63) >> 4;
    const int wm = (wv >> 1) * 64;
    const int wn = (wv & 1) * 64;

    // panel swizzle: consecutive 16x-by-gy panels for L2 weight reuse
    const int gx = gridDim.x, gy = gridDim.y;
    int f = blockIdx.y * gx + blockIdx.x;
    int nfull = gx >> 4;
    int fullB = nfull * 16 * gy;
    int bx, by;
    if (f < fullB) {
        int p = f / (16 * gy);
        int r = f - p * (16 * gy);
        bx = p * 16 + (r & 15);
        by = r >> 4;
    } else {
        int r = f - fullB;
        int w = gx - (nfull << 4);
        bx = (nfull << 4) + r % w;
        by = r / w;
    }
    const int m0 = by * 128;
    const int n0 = bx * 128;
    const int kb = K / KSPLIT;
    const int k_beg = (KSPLIT > 1) ? blockIdx.z * kb : 0;
    const int k_end = k_beg + kb;

    f32x4 acc[4][4];
    #pragma unroll
    for (int i = 0; i < 4; i++)
        #pragma unroll
        for (int j = 0; j < 4; j++)
            #pragma unroll
            for (int r = 0; r < 4; r++) acc[i][j][r] = 0.0f;

    const int rsw = (ln >> 1) & 3;   // XOR bank swizzle key for fragment reads

    for (int k0 = k_beg; k0 < k_end; k0 += 32) {
        #pragma unroll
        for (int r = 0; r < 2; r++) {
            int ci = r * 256 + tid;
            int row = ci >> 2;
            int lc = (ci & 3) ^ ((row >> 1) & 3);   // swizzled logical chunk
            gload_lds16(A + (size_t)(m0 + row) * K + k0 + lc * 8,
                        At + (size_t)(r * 256 + wv * 64) * 8);
            gload_lds16(W + (size_t)(n0 + row) * K + k0 + lc * 8,
                        Bt + (size_t)(r * 256 + wv * 64) * 8);
        }
        __syncthreads();
        bf16x8 af[4], bfg[4];
        #pragma unroll
        for (int i = 0; i < 4; i++)
            af[i] = *(const bf16x8*)&At[(wm + i * 16 + ln) * 32 + (quad ^ rsw) * 8];
        #pragma unroll
        for (int j = 0; j < 4; j++)
            bfg[j] = *(const bf16x8*)&Bt[(wn + j * 16 + ln) * 32 + (quad ^ rsw) * 8];
        #pragma unroll
        for (int i = 0; i < 4; i++)
            #pragma unroll
            for (int j = 0; j < 4; j++)
                acc[i][j] = __builtin_amdgcn_mfma_f32_16x16x32_bf16(af[i], bfg[j], acc[i][j], 0, 0, 0);
        __syncthreads();
    }

    const bool addBias = (EPI != 3) && (KSPLIT == 1 || blockIdx.z == 0);
    #pragma unroll
    for (int j = 0; j < 4; j++) {
        int col = n0 + wn + j * 16 + ln;
        float bv = addBias ? bias[col] : 0.0f;
        #pragma unroll
        for (int i = 0; i < 4; i++) {
            int rowb = m0 + wm + i * 16 + quad * 4;
            #pragma unroll
            for (int r = 0; r < 4; r++) {
                float v = acc[i][j][r] + bv;
                size_t idx = (size_t)(rowb + r) * N + col;
                if (EPI == 0) {
                    outb[idx] = __float2bfloat16(v);
                } else if (EPI == 1) {
                    outb[idx] = __float2bfloat16(0.5f * v * (1.0f + erff(v * 0.70710678118654752f)));
                } else if (EPI == 2) {
                    if (KSPLIT > 1) atomicAdd(&outf[idx], v);
                    else outf[idx] += v;
                } else {
                    outf[idx] = v;
                }
            }
        }
    }
}

// ---------------- V transpose: qkv V-part [t][h*64+d] -> vT [h][d][t] ----------------
__global__ __launch_bounds__(256) void vtrans_kernel(const bf16* __restrict__ qkv,
                                                     bf16* __restrict__ vT) {
    const int h = blockIdx.x;
    const int t0 = blockIdx.y * 64;
    __shared__ __bf16 tl[64][72];
    const int tid = threadIdx.x;
    const int rhalf = tid >> 3;          // 0..31
    const int c8 = (tid & 7) * 8;
    #pragma unroll
    for (int rr = 0; rr < 2; rr++) {
        int row = rhalf + 32 * rr;       // t within tile
        bf16x8 v = *(const bf16x8*)(qkv + (size_t)(t0 + row) * (3 * CC) + 2 * CC + h * DD + c8);
        #pragma unroll
        for (int i = 0; i < 8; i++) tl[c8 + i][row] = v[i];
    }
    __syncthreads();
    #pragma unroll
    for (int rr = 0; rr < 2; rr++) {
        int d = rhalf + 32 * rr;
        bf16x8 o;
        #pragma unroll
        for (int i = 0; i < 8; i++) o[i] = tl[d][c8 + i];
        *(bf16x8*)(vT + (size_t)(h * DD + d) * TT + t0 + c8) = o;
    }
}

// ---------------- flash attention v2 (causal) ----------------
// grid (H, T/128), 256 threads = 4 waves; wave handles 32 q-rows.
// Computes S^T = K·Q^T (keys in MFMA rows -> cheap softmax), PV with pre-transposed V.
__global__ __launch_bounds__(256) void attn_kernel(const bf16* __restrict__ qkv,
                                                   const bf16* __restrict__ vT,
                                                   bf16* __restrict__ y) {
    const int h = blockIdx.x;
    const int q0 = blockIdx.y * 128;
    const int tid = threadIdx.x;
    const int wq = tid >> 6;
    const int ln = tid & 15;
    const int quad = (tid & 63) >> 4;
    const int wr0 = q0 + wq * 32;

    __shared__ bf16 Kt[64 * 64];         // [key][d], XOR-swizzled 16B chunks
    __shared__ bf16 Vt[64 * 64];         // [d][t],  XOR-swizzled 16B chunks
    __shared__ bf16 Pt[4][32 * 72];      // per-wave P[qlocal][j], stride 72 (144B, 16B-aligned)

    // Q fragments as MFMA B-operand: lane n=ln -> q row; k = d
    bf16x8 qf[2][2];
    #pragma unroll
    for (int qi = 0; qi < 2; qi++)
        #pragma unroll
        for (int ks = 0; ks < 2; ks++)
            qf[qi][ks] = *(const bf16x8*)(qkv + (size_t)(wr0 + qi * 16 + ln) * (3 * CC) + h * DD + ks * 32 + quad * 8);

    f32x4 oy[2][4];                      // [q group][d group]
    float mrow[2], lrow[2];
    #pragma unroll
    for (int i = 0; i < 2; i++) {
        #pragma unroll
        for (int j = 0; j < 4; j++)
            #pragma unroll
            for (int r = 0; r < 4; r++) oy[i][j][r] = 0.0f;
        mrow[i] = -INFINITY;
        lrow[i] = 0.0f;
    }

    const int ntiles = q0 / 64 + 2;
    for (int kt = 0; kt < ntiles; kt++) {
        const int kt0 = kt * 64;
        // stage K tile and V^T tile via async 16B global->LDS, XOR chunk swizzle
        #pragma unroll
        for (int r = 0; r < 2; r++) {
            int ci = r * 256 + tid;
            int row = ci >> 3;
            int lc = (ci & 7) ^ (row & 7);
            gload_lds16(qkv + (size_t)(kt0 + row) * (3 * CC) + CC + h * DD + lc * 8,
                        Kt + (size_t)(r * 256 + wq * 64) * 8);
            gload_lds16(vT + (size_t)(h * DD + row) * TT + kt0 + lc * 8,
                        Vt + (size_t)(r * 256 + wq * 64) * 8);
        }
        __syncthreads();

        if (kt0 <= wr0) {
            // S^T: A = K rows (m=key), B = Q rows (n=q)
            bf16x8 kf[4][2];
            #pragma unroll
            for (int ki = 0; ki < 4; ki++)
                #pragma unroll
                for (int ks = 0; ks < 2; ks++) {
                    int Rk = ki * 16 + ln;
                    kf[ki][ks] = *(const bf16x8*)&Kt[Rk * 64 + (((ks * 4 + quad) ^ (Rk & 7))) * 8];
                }
            f32x4 st[4][2];
            #pragma unroll
            for (int ki = 0; ki < 4; ki++)
                #pragma unroll
                for (int qi = 0; qi < 2; qi++)
                    #pragma unroll
                    for (int r = 0; r < 4; r++) st[ki][qi][r] = 0.0f;
            #pragma unroll
            for (int ks = 0; ks < 2; ks++)
                #pragma unroll
                for (int ki = 0; ki < 4; ki++)
                    #pragma unroll
                    for (int qi = 0; qi < 2; qi++)
                        st[ki][qi] = __builtin_amdgcn_mfma_f32_16x16x32_bf16(kf[ki][ks], qf[qi][ks], st[ki][qi], 0, 0, 0);

            // online softmax: row q = wr0 + qi*16 + ln holds its 16 keys in this lane (x4 quads = 64)
            const float scale = 0.125f;
            float alpha[2];
            #pragma unroll
            for (int qi = 0; qi < 2; qi++) {
                int q = wr0 + qi * 16 + ln;
                float sv[4][4];
                float mx = -INFINITY;
                #pragma unroll
                for (int ki = 0; ki < 4; ki++)
                    #pragma unroll
                    for (int r = 0; r < 4; r++) {
                        float t = st[ki][qi][r] * scale;
                        int key = kt0 + ki * 16 + quad * 4 + r;
                        if (key > q) t = -INFINITY;
                        sv[ki][r] = t;
                        mx = fmaxf(mx, t);
                    }
                mx = fmaxf(mx, __shfl_xor(mx, 16, 64));
                mx = fmaxf(mx, __shfl_xor(mx, 32, 64));
                float mnew = fmaxf(mrow[qi], mx);
                alpha[qi] = __expf(mrow[qi] - mnew);
                mrow[qi] = mnew;
                float ps = 0.0f;
                #pragma unroll
                for (int ki = 0; ki < 4; ki++)
                    #pragma unroll
                    for (int r = 0; r < 4; r++) {
                        float p = __expf(sv[ki][r] - mnew);
                        ps += p;
                        Pt[wq][(qi * 16 + ln) * 72 + ki * 16 + quad * 4 + r] = __float2bfloat16(p);
                    }
                ps += __shfl_xor(ps, 16, 64);
                ps += __shfl_xor(ps, 32, 64);
                lrow[qi] = lrow[qi] * alpha[qi] + ps;
            }

            // rescale O (rows live at quad*4+r, alpha lives at lane ln=row)
            #pragma unroll
            for (int i = 0; i < 2; i++)
                #pragma unroll
                for (int r = 0; r < 4; r++) {
                    float a = __shfl(alpha[i], quad * 4 + r, 16);
                    #pragma unroll
                    for (int dn = 0; dn < 4; dn++) oy[i][dn][r] *= a;
                }

            // O += P @ V : A = P rows (m=q), B = V^T rows (n=d)
            bf16x8 pf[2][2], vf[4][2];
            #pragma unroll
            for (int i = 0; i < 2; i++)
                #pragma unroll
                for (int ks = 0; ks < 2; ks++)
                    pf[i][ks] = *(const bf16x8*)&Pt[wq][(i * 16 + ln) * 72 + ks * 32 + quad * 8];
            #pragma unroll
            for (int dn = 0; dn < 4; dn++)
                #pragma unroll
                for (int ks = 0; ks < 2; ks++) {
                    int Rd = dn * 16 + ln;
                    vf[dn][ks] = *(const bf16x8*)&Vt[Rd * 64 + (((ks * 4 + quad) ^ (Rd & 7))) * 8];
                }
            #pragma unroll
            for (int ks = 0; ks < 2; ks++)
                #pragma unroll
                for (int i = 0; i < 2; i++)
                    #pragma unroll
                    for (int dn = 0; dn < 4; dn++)
                        oy[i][dn] = __builtin_amdgcn_mfma_f32_16x16x32_bf16(pf[i][ks], vf[dn][ks], oy[i][dn], 0, 0, 0);
        }
        __syncthreads();
    }

    // epilogue: y = O / l
    #pragma unroll
    for (int i = 0; i < 2; i++)
        #pragma unroll
        for (int r = 0; r < 4; r++) {
            float linv = 1.0f / __shfl(lrow[i], quad * 4 + r, 16);
            int row = wr0 + i * 16 + quad * 4 + r;
            #pragma unroll
            for (int dn = 0; dn < 4; dn++)
                y[(size_t)row * CC + h * DD + dn * 16 + ln] = __float2bfloat16(oy[i][dn][r] * linv);
        }
}

// ---------------- launch ----------------
extern "C" void kernel_launch(void* const* d_in, const int* in_sizes, int n_in,
                              void* d_out, int out_size, void* d_ws, size_t ws_size,
                              hipStream_t stream) {
    const int*   ids    = (const int*)d_in[0];
    const float* wte    = (const float*)d_in[1];
    const float* wpe    = (const float*)d_in[2];
    const float* ln1_w  = (const float*)d_in[3];
    const float* ln1_b  = (const float*)d_in[4];
    const float* attn_w = (const float*)d_in[5];
    const float* attn_b = (const float*)d_in[6];
    const float* proj_w = (const float*)d_in[7];
    const float* proj_b = (const float*)d_in[8];
    const float* ln2_w  = (const float*)d_in[9];
    const float* ln2_b  = (const float*)d_in[10];
    const float* fc_w   = (const float*)d_in[11];
    const float* fc_b   = (const float*)d_in[12];
    const float* fcp_w  = (const float*)d_in[13];
    const float* fcp_b  = (const float*)d_in[14];
    const float* lnf_w  = (const float*)d_in[15];
    const float* lnf_b  = (const float*)d_in[16];

    char* ws = (char*)d_ws;
    float* x    = (float*)(ws);                     // 8 MB fp32 residual
    bf16* hbuf  = (bf16*)(ws + 8388608);            // 4 MB  (T x C)
    bf16* g4buf = (bf16*)(ws + 12582912);           // 16 MB (T x 4C); reused as vT during attention
    bf16* qkvb  = (bf16*)(ws + 29360128);           // 12 MB (T x 3C)
    bf16* ybuf  = (bf16*)(ws + 41943040);           // 4 MB  (T x C)
    bf16* wbuf  = (bf16*)(ws + 46137344);           // 62.5 MB (max VOCAB x C)
    bf16* vtb   = g4buf;                            // 4 MB vT [h][d][t]

    embed_kernel<<<TT, 256, 0, stream>>>(ids, wte, wpe, x);

    for (int l = 0; l < LL; l++) {
        ln_kernel<<<TT, 256, 0, stream>>>(x, ln1_w + l * CC, ln1_b + l * CC, hbuf);

        cvt_kernel<<<(3 * CC * CC) / 1024, 256, 0, stream>>>(attn_w + (size_t)l * 3 * CC * CC, wbuf, 3 * CC * CC);
        gemm_bt<0, 1><<<dim3(3 * CC / 128, TT / 128), 256, 0, stream>>>(hbuf, wbuf, attn_b + l * 3 * CC,
                                                                        qkvb, nullptr, TT, 3 * CC, CC);

        vtrans_kernel<<<dim3(HH, TT / 64), 256, 0, stream>>>(qkvb, vtb);
        attn_kernel<<<dim3(HH, TT / 128), 256, 0, stream>>>(qkvb, vtb, ybuf);

        cvt_kernel<<<(CC * CC) / 1024, 256, 0, stream>>>(proj_w + (size_t)l * CC * CC, wbuf, CC * CC);
        gemm_bt<2, 2><<<dim3(CC / 128, TT / 128, 2), 256, 0, stream>>>(ybuf, wbuf, proj_b + l * CC,
                                                                       nullptr, x, TT, CC, CC);

        ln_kernel<<<TT, 256, 0, stream>>>(x, ln2_w + l * CC, ln2_b + l * CC, hbuf);

        cvt_kernel<<<(4 * CC * CC) / 1024, 256, 0, stream>>>(fc_w + (size_t)l * 4 * CC * CC, wbuf, 4 * CC * CC);
        gemm_bt<1, 1><<<dim3(4 * CC / 128, TT / 128), 256, 0, stream>>>(hbuf, wbuf, fc_b + l * 4 * CC,
                                                                        g4buf, nullptr, TT, 4 * CC, CC);

        cvt_kernel<<<(4 * CC * CC) / 1024, 256, 0, stream>>>(fcp_w + (size_t)l * 4 * CC * CC, wbuf, 4 * CC * CC);
        gemm_bt<2, 2><<<dim3(CC / 128, TT / 128, 2), 256, 0, stream>>>(g4buf, wbuf, fcp_b + l * CC,
                                                                       nullptr, x, TT, CC, 4 * CC);
    }

    ln_kernel<<<TT, 256, 0, stream>>>(x, lnf_w, lnf_b, hbuf);
    cvt_kernel<<<(VOCAB_N * CC) / 1024, 256, 0, stream>>>(wte, wbuf, VOCAB_N * CC);
    gemm_bt<3, 1><<<dim3(VOCAB_N / 128, TT / 128), 256, 0, stream>>>(hbuf, wbuf, nullptr,
                                                                     nullptr, (float*)d_out, TT, VOCAB_N, CC);
}